// Round 7
// baseline (177.603 us; speedup 1.0000x reference)
//
#include <hip/hip_runtime.h>
#include <hip/hip_bf16.h>

// LightGCN: two rounds of edge aggregation.
//   h[i]   = sum_{e: dst[e]==i} x[src[e]]
//   out[i] = sum_{e: dst[e]==i} relu(h)[src[e]]
//
// Round 19 (R18 fix: aggregate grid must cover the full RANK space):
//   R18's degree-ranked nodemap permutes nodes within each bin's 128-slot
//   rank space (n_bins*128 = 100096 > n_nodes). The grid only covered
//   100000 ranks, and zero-degree out-of-range nids sort FIRST, pushing the
//   last bin's 32 valid nodes to ranks >= 96 -> never processed -> absmax 58.
//   Fix: agg_blocks = n_bins*BIN_NODES/32 = 3128 (full rank space); the
//   node < n_nodes guard handles the padding ranks.
//   - degree-balanced aggregate waves (R18): bin_sort emits nodemap so the
//     8 nodes in a wave have adjacent degrees -> balanced gather loops.
//   - partition: LDS-sorted tile -> run-coalesced span writes (R17).
//   - ReLU folded into pass-0 aggregate's bf16 write.

#define N_FEAT    64
#define BIN_SHIFT 7
#define BIN_NODES 128
#define CAPBIN    2048             // edges per bin (mean 1600, +11 sigma)
#define NB_H      784              // >= n_bins (782)
#define NSCAN     1024             // padded hist size for the 4-per-thread scan
#define GSTRIDE   16               // one gcur cursor per 64B line
#define TILE      4096
#define NPTR      (BIN_NODES + 1)  // nodeptr entries per bin

typedef unsigned int u32;
typedef unsigned short u16;
typedef __attribute__((ext_vector_type(8))) unsigned short u16x8;
typedef __attribute__((ext_vector_type(4))) unsigned int u32x4;
typedef __attribute__((ext_vector_type(2))) float f32x2;

__device__ inline u16 f2bf(float f) {          // RTNE
    u32 u = __builtin_bit_cast(u32, f);
    return (u16)((u + 0x7FFFu + ((u >> 16) & 1u)) >> 16);
}

// ---- pass 1: LDS-sorted tile partition + x->bf16 convert ----
__global__ __launch_bounds__(256) void partition_convert_kernel(
    const float* __restrict__ xf, u16* __restrict__ xb, int n_elems,
    const int* __restrict__ src, const int* __restrict__ dst,
    u32* __restrict__ gcur,        // [n_bins*GSTRIDE] padded cursors (zeroed)
    u32* __restrict__ cbdata,      // [n_bins*CAPBIN] packed (nid7<<17)|src
    int n_edges, int n_bins, int part_blocks)
{
    __shared__ u32 hist[NSCAN];        // 4 KB
    __shared__ u32 starts[NSCAN];      // 4 KB (tile-local exclusive prefix)
    __shared__ u32 lpos[NSCAN];        // 4 KB
    __shared__ u32 wcur[NB_H];         // 3.1 KB (global span base per bin)
    __shared__ u32 sortbuf[TILE];      // 16 KB
    __shared__ u16 binid[TILE];        // 8 KB
    __shared__ u32 wsum[4];

    const int tid = threadIdx.x;

    if ((int)blockIdx.x >= part_blocks) {      // ---- convert x -> bf16 ----
        int i = (((int)blockIdx.x - part_blocks) * 256 + tid) * 8;
        if (i < n_elems) {
            float4 a = *(const float4*)(xf + i);
            float4 b = *(const float4*)(xf + i + 4);
            u16x8 r;
            r[0]=f2bf(a.x); r[1]=f2bf(a.y); r[2]=f2bf(a.z); r[3]=f2bf(a.w);
            r[4]=f2bf(b.x); r[5]=f2bf(b.y); r[6]=f2bf(b.z); r[7]=f2bf(b.w);
            *(u16x8*)(xb + i) = r;
        }
        return;
    }

    const int tbase = (int)blockIdx.x * TILE;
    const int tend  = min(tbase + TILE, n_edges);

    for (int i = tid; i < NSCAN; i += 256) { hist[i] = 0; lpos[i] = 0; }
    __syncthreads();

    for (int e = tbase + tid; e < tend; e += 256)      // pass A: count
        atomicAdd(&hist[(u32)dst[e] >> BIN_SHIFT], 1u);
    __syncthreads();

    // Tile-local exclusive scan of hist[0..NSCAN): 4 slots/thread + wave scan.
    {
        const int b0 = tid * 4;
        u32 h0 = hist[b0], h1 = hist[b0+1], h2 = hist[b0+2], h3 = hist[b0+3];
        u32 s  = h0 + h1 + h2 + h3;
        u32 inc = s;
        #pragma unroll
        for (int d = 1; d < 64; d <<= 1) {
            u32 o = __shfl_up(inc, d);
            if ((tid & 63) >= d) inc += o;
        }
        if ((tid & 63) == 63) wsum[tid >> 6] = inc;
        __syncthreads();
        u32 woff = 0;
        #pragma unroll
        for (int k = 0; k < 4; ++k) if (k < (tid >> 6)) woff += wsum[k];
        u32 excl = woff + inc - s;
        starts[b0]   = excl;
        starts[b0+1] = excl + h0;
        starts[b0+2] = excl + h0 + h1;
        starts[b0+3] = excl + h0 + h1 + h2;
    }
    __syncthreads();

    // Reserve global spans (rotated start to spread cursor-line contention).
    const int rot = (int)(((u32)blockIdx.x * 193u) % (u32)n_bins);
    for (int i = tid; i < n_bins; i += 256) {
        int b = i + rot; if (b >= n_bins) b -= n_bins;
        u32 h = hist[b];
        if (h) wcur[b] = atomicAdd(&gcur[b * GSTRIDE], h);
    }
    __syncthreads();

    for (int e = tbase + tid; e < tend; e += 256) {    // pass B: LDS place
        int d = dst[e];                                 // L2-hot re-read
        int s = src[e];
        u32 b   = (u32)d >> BIN_SHIFT;
        u32 pos = starts[b] + atomicAdd(&lpos[b], 1u);
        sortbuf[pos] = ((u32)(d & (BIN_NODES - 1)) << 17) | (u32)s;
        binid[pos]   = (u16)b;
    }
    __syncthreads();

    // pass C: linear sweep -> run-coalesced global writes.
    const int cnt = tend - tbase;
    for (int j = tid; j < cnt; j += 256) {
        u32 b   = binid[j];
        u32 rel = wcur[b] + ((u32)j - starts[b]);
        if (rel < CAPBIN)
            cbdata[(size_t)b * CAPBIN + rel] = sortbuf[j];
    }
}

// ---- pass 2: per-bin LDS counting sort by node -> CSR + degree-ranked map --
__global__ __launch_bounds__(256) void bin_sort_kernel(
    u32* __restrict__ cbdata,          // in: (nid7<<17)|src   out: src (sorted)
    const u32* __restrict__ gcur,
    u32* __restrict__ nodeptr,         // [n_bins*NPTR] absolute offsets
    u32* __restrict__ nodemap,         // [n_bins*BIN_NODES] rank -> local nid
    int n_bins)
{
    __shared__ u32 hist[BIN_NODES];
    __shared__ u32 ptrs[NPTR];
    __shared__ u32 lpos[BIN_NODES];
    __shared__ u32 sl[CAPBIN];         // 8 KB staging
    __shared__ u32 dh[64];             // degree histogram (key = min(deg,63))
    __shared__ u32 dptr[64];
    __shared__ u32 dpos[64];

    const int tid = threadIdx.x;
    const int bin = blockIdx.x;
    if (bin >= n_bins) return;

    if (tid < BIN_NODES) { hist[tid] = 0; lpos[tid] = 0; }
    if (tid < 64) { dh[tid] = 0; dpos[tid] = 0; }
    __syncthreads();

    int cnt = (int)gcur[bin * GSTRIDE];
    if (cnt > CAPBIN) cnt = CAPBIN;
    u32* bd = cbdata + (size_t)bin * CAPBIN;

    for (int j = tid; j < cnt; j += 256)               // count
        atomicAdd(&hist[bd[j] >> 17], 1u);
    __syncthreads();

    if (tid < 64) {                    // wave 0: scan 128 counters (2/lane)
        u32 a = hist[2 * tid], b = hist[2 * tid + 1];
        u32 s = a + b;
        #pragma unroll
        for (int d = 1; d < 64; d <<= 1) {
            u32 o = __shfl_up(s, d);
            if (tid >= d) s += o;
        }
        ptrs[2 * tid]     = s - a - b;
        ptrs[2 * tid + 1] = s - b;
        if (tid == 63) ptrs[BIN_NODES] = s;
    }
    if (tid < BIN_NODES)               // degree histogram (key clamped)
        atomicAdd(&dh[min(hist[tid], 63u)], 1u);
    __syncthreads();

    if (tid < 64) {                    // wave 0: exclusive scan of dh
        u32 v = dh[tid];
        u32 s = v;
        #pragma unroll
        for (int d = 1; d < 64; d <<= 1) {
            u32 o = __shfl_up(s, d);
            if (tid >= d) s += o;
        }
        dptr[tid] = s - v;
    }
    __syncthreads();

    if (tid < BIN_NODES) {             // place nodes into degree-rank order
        u32 key  = min(hist[tid], 63u);
        u32 rank = dptr[key] + atomicAdd(&dpos[key], 1u);
        nodemap[(size_t)bin * BIN_NODES + rank] = (u32)tid;
    }

    for (int j = tid; j < cnt; j += 256) {             // place into LDS
        u32 p   = bd[j];
        u32 nid = p >> 17;
        u32 pos = ptrs[nid] + atomicAdd(&lpos[nid], 1u);
        sl[pos] = p & 0x1FFFFu;
    }
    __syncthreads();

    const u32 base = (u32)bin * CAPBIN;
    for (int j = tid; j < cnt; j += 256)               // coalesced writeback
        bd[j] = sl[j];
    if (tid < NPTR)
        nodeptr[(size_t)bin * NPTR + tid] = base + ptrs[tid];
}

// ---- aggregate: one 8-lane group per degree-rank, CSR spans, no LDS ----
// pass 0: out_bf[node] = bf16(relu(sum))   pass 1: out_f[node] = sum (fp32)
__global__ __launch_bounds__(256) void aggregate_kernel(
    const u16* __restrict__ xin,
    const u32* __restrict__ csorted,   // sorted src ids
    const u32* __restrict__ nodeptr,
    const u32* __restrict__ nodemap,
    u16* __restrict__ out_bf,
    float* __restrict__ out_f,
    int n_nodes, int pass)
{
    const int tid  = threadIdx.x;

    const int w    = tid >> 6;
    const int lane = tid & 63;
    const int grp  = lane >> 3;
    const int sub  = lane & 7;           // 16B chunk of the 128B bf16 row
    const char* xc = (const char*)xin;

    const int nl   = w * 8 + grp;        // 0..31
    const int rg   = (int)blockIdx.x * 32 + nl;        // global degree-rank
    const int bin  = rg >> BIN_SHIFT;
    const int rank = rg & (BIN_NODES - 1);
    const int nid  = (int)nodemap[(size_t)bin * BIN_NODES + rank];
    const int node = bin * BIN_NODES + nid;

    const int s0  = (int)nodeptr[(size_t)bin * NPTR + nid];
    const int s1  = (int)nodeptr[(size_t)bin * NPTR + nid + 1];

    f32x2 a0={0.f,0.f}, a1={0.f,0.f}, a2={0.f,0.f}, a3={0.f,0.f};

    // Batch-8 id loads (one coalesced load per 8 edges), shfl-broadcast.
    for (int jb = s0; jb < s1; jb += 8) {
        u32 myid = 0;
        if (jb + sub < s1) myid = csorted[jb + sub];
        const int m = min(8, s1 - jb);
        #pragma unroll 1
        for (int k = 0; k < m; ++k) {
            u32 s = (u32)__shfl((int)myid, (lane & 56) + k, 64);
            u32x4 v = *(const u32x4*)(xc + ((size_t)s << 7) + (sub << 4));
            a0 += (f32x2){ __builtin_bit_cast(float, v[0] << 16),
                           __builtin_bit_cast(float, v[0] & 0xFFFF0000u) };
            a1 += (f32x2){ __builtin_bit_cast(float, v[1] << 16),
                           __builtin_bit_cast(float, v[1] & 0xFFFF0000u) };
            a2 += (f32x2){ __builtin_bit_cast(float, v[2] << 16),
                           __builtin_bit_cast(float, v[2] & 0xFFFF0000u) };
            a3 += (f32x2){ __builtin_bit_cast(float, v[3] << 16),
                           __builtin_bit_cast(float, v[3] & 0xFFFF0000u) };
        }
    }

    if (node < n_nodes) {
        if (pass == 0) {                 // 64 lanes x 16B: 8 bf16 rows, relu'd
            u16x8 o;
            o[0]=f2bf(fmaxf(a0.x,0.f)); o[1]=f2bf(fmaxf(a0.y,0.f));
            o[2]=f2bf(fmaxf(a1.x,0.f)); o[3]=f2bf(fmaxf(a1.y,0.f));
            o[4]=f2bf(fmaxf(a2.x,0.f)); o[5]=f2bf(fmaxf(a2.y,0.f));
            o[6]=f2bf(fmaxf(a3.x,0.f)); o[7]=f2bf(fmaxf(a3.y,0.f));
            *(u16x8*)(out_bf + (size_t)node * N_FEAT + sub * 8) = o;
        } else {                         // 64 lanes x 32B: 8 fp32 rows
            float* dp = out_f + (size_t)node * N_FEAT + sub * 8;
            *(float4*)dp       = (float4){a0.x, a0.y, a1.x, a1.y};
            *(float4*)(dp + 4) = (float4){a2.x, a2.y, a3.x, a3.y};
        }
    }
}

extern "C" void kernel_launch(void* const* d_in, const int* in_sizes, int n_in,
                              void* d_out, int out_size, void* d_ws, size_t ws_size,
                              hipStream_t stream) {
    const float* x          = (const float*)d_in[0];
    const int*   edge_index = (const int*)d_in[1];

    const int n_edges = in_sizes[1] / 2;          // (2, N_EDGES) row-major
    const int* src = edge_index;                  // row 0
    const int* dst = edge_index + n_edges;        // row 1

    const int n_nodes = out_size / N_FEAT;                      // 100000
    const int n_bins  = (n_nodes + BIN_NODES - 1) >> BIN_SHIFT; // 782
    float* out = (float*)d_out;

    const size_t xb_bytes    = (size_t)out_size * sizeof(u16);             // 12.8 MB
    const size_t hb_bytes    = (size_t)out_size * sizeof(u16);             // 12.8 MB
    const size_t cb_bytes    = (size_t)n_bins * CAPBIN * sizeof(u32);      // 6.4 MB
    const size_t np_bytes    = (size_t)n_bins * NPTR * sizeof(u32);        // 0.4 MB
    const size_t nm_bytes    = (size_t)n_bins * BIN_NODES * sizeof(u32);   // 0.4 MB
    const size_t gcur_bytes  = (size_t)NB_H * GSTRIDE * sizeof(u32);       // 50 KB

    char* w = (char*)d_ws;
    u16* xb      = (u16*)w;              w += xb_bytes;
    u16* hb      = (u16*)w;              w += hb_bytes;
    u32* cbdata  = (u32*)w;              w += cb_bytes;
    u32* nodeptr = (u32*)w;              w += np_bytes;
    u32* nodemap = (u32*)w;              w += nm_bytes;
    u32* gcur    = (u32*)w;

    hipMemsetAsync(gcur, 0, gcur_bytes, stream);

    const int part_blocks = (n_edges + TILE - 1) / TILE;     // 306
    const int conv_blocks = (out_size / 8 + 255) / 256;      // 3125
    partition_convert_kernel<<<part_blocks + conv_blocks, 256, 0, stream>>>(
        x, xb, out_size, src, dst, gcur, cbdata, n_edges, n_bins, part_blocks);

    bin_sort_kernel<<<n_bins, 256, 0, stream>>>(cbdata, gcur, nodeptr, nodemap, n_bins);

    // Cover the FULL rank space (n_bins*128 = 100096), not just n_nodes:
    // zero-degree padding nids sort first and displace valid nodes to high
    // ranks, so every rank must be visited (R18 bug).
    const int agg_blocks = (n_bins * BIN_NODES) / 32;        // 3128
    aggregate_kernel<<<agg_blocks, 256, 0, stream>>>(xb, cbdata, nodeptr, nodemap, hb, nullptr, n_nodes, 0);
    aggregate_kernel<<<agg_blocks, 256, 0, stream>>>(hb, cbdata, nodeptr, nodemap, nullptr, out, n_nodes, 1);
}

// Round 8
// 169.613 us; speedup vs baseline: 1.0471x; 1.0471x over previous
//
#include <hip/hip_runtime.h>
#include <hip/hip_bf16.h>

// LightGCN: two rounds of edge aggregation.
//   h[i]   = sum_{e: dst[e]==i} x[src[e]]
//   out[i] = sum_{e: dst[e]==i} relu(h)[src[e]]
//
// Round 20 (src-ordered gathers; nodemap reverted):
//   R19 refuted the divergence theory (degree-balanced waves: +7us, not
//   -20): aggregates are gather-THROUGHPUT-bound (~160MB of 128B random
//   rows per dispatch from a 12.8MB buffer; L2 hit ~31%, ~110MB over the
//   L3 fabric). Fix the ORDER instead of the schedule: bin_sort's counting
//   sort key widens from nid to (nid<<3)|(src>>14), so every node's edge
//   segment is sorted by src-block (2MB windows). All blocks start
//   together with near-equal work -> the whole GPU walks src 0..100K in
//   loose lockstep -> outstanding gathers cluster in an ~L2-sized window
//   -> the 12.5x row reuse lands in L2 instead of L3.
//   - nodemap/degree-rank machinery removed (R19: regression).
//   - partition: LDS-sorted tile -> run-coalesced span writes (R17).
//   - aggregate: R17 structure (no LDS, batch-8 id loads + shfl).
//   - ReLU folded into pass-0 aggregate's bf16 write.

#define N_FEAT    64
#define BIN_SHIFT 7
#define BIN_NODES 128
#define CAPBIN    2048             // edges per bin (mean 1600, +11 sigma)
#define NB_H      784              // >= n_bins (782)
#define NSCAN     1024             // padded hist size for the 4-per-thread scan
#define GSTRIDE   16               // one gcur cursor per 64B line
#define TILE      4096
#define NPTR      (BIN_NODES + 1)  // nodeptr entries per bin
#define SRCSH     14               // src subkey shift: 8 blocks of 16K nodes

typedef unsigned int u32;
typedef unsigned short u16;
typedef __attribute__((ext_vector_type(8))) unsigned short u16x8;
typedef __attribute__((ext_vector_type(4))) unsigned int u32x4;
typedef __attribute__((ext_vector_type(2))) float f32x2;

__device__ inline u16 f2bf(float f) {          // RTNE
    u32 u = __builtin_bit_cast(u32, f);
    return (u16)((u + 0x7FFFu + ((u >> 16) & 1u)) >> 16);
}

// ---- pass 1: LDS-sorted tile partition + x->bf16 convert ----
__global__ __launch_bounds__(256) void partition_convert_kernel(
    const float* __restrict__ xf, u16* __restrict__ xb, int n_elems,
    const int* __restrict__ src, const int* __restrict__ dst,
    u32* __restrict__ gcur,        // [n_bins*GSTRIDE] padded cursors (zeroed)
    u32* __restrict__ cbdata,      // [n_bins*CAPBIN] packed (nid7<<17)|src
    int n_edges, int n_bins, int part_blocks)
{
    __shared__ u32 hist[NSCAN];        // 4 KB
    __shared__ u32 starts[NSCAN];      // 4 KB (tile-local exclusive prefix)
    __shared__ u32 lpos[NSCAN];        // 4 KB
    __shared__ u32 wcur[NB_H];         // 3.1 KB (global span base per bin)
    __shared__ u32 sortbuf[TILE];      // 16 KB
    __shared__ u16 binid[TILE];        // 8 KB
    __shared__ u32 wsum[4];

    const int tid = threadIdx.x;

    if ((int)blockIdx.x >= part_blocks) {      // ---- convert x -> bf16 ----
        int i = (((int)blockIdx.x - part_blocks) * 256 + tid) * 8;
        if (i < n_elems) {
            float4 a = *(const float4*)(xf + i);
            float4 b = *(const float4*)(xf + i + 4);
            u16x8 r;
            r[0]=f2bf(a.x); r[1]=f2bf(a.y); r[2]=f2bf(a.z); r[3]=f2bf(a.w);
            r[4]=f2bf(b.x); r[5]=f2bf(b.y); r[6]=f2bf(b.z); r[7]=f2bf(b.w);
            *(u16x8*)(xb + i) = r;
        }
        return;
    }

    const int tbase = (int)blockIdx.x * TILE;
    const int tend  = min(tbase + TILE, n_edges);

    for (int i = tid; i < NSCAN; i += 256) { hist[i] = 0; lpos[i] = 0; }
    __syncthreads();

    for (int e = tbase + tid; e < tend; e += 256)      // pass A: count
        atomicAdd(&hist[(u32)dst[e] >> BIN_SHIFT], 1u);
    __syncthreads();

    // Tile-local exclusive scan of hist[0..NSCAN): 4 slots/thread + wave scan.
    {
        const int b0 = tid * 4;
        u32 h0 = hist[b0], h1 = hist[b0+1], h2 = hist[b0+2], h3 = hist[b0+3];
        u32 s  = h0 + h1 + h2 + h3;
        u32 inc = s;
        #pragma unroll
        for (int d = 1; d < 64; d <<= 1) {
            u32 o = __shfl_up(inc, d);
            if ((tid & 63) >= d) inc += o;
        }
        if ((tid & 63) == 63) wsum[tid >> 6] = inc;
        __syncthreads();
        u32 woff = 0;
        #pragma unroll
        for (int k = 0; k < 4; ++k) if (k < (tid >> 6)) woff += wsum[k];
        u32 excl = woff + inc - s;
        starts[b0]   = excl;
        starts[b0+1] = excl + h0;
        starts[b0+2] = excl + h0 + h1;
        starts[b0+3] = excl + h0 + h1 + h2;
    }
    __syncthreads();

    // Reserve global spans (rotated start to spread cursor-line contention).
    const int rot = (int)(((u32)blockIdx.x * 193u) % (u32)n_bins);
    for (int i = tid; i < n_bins; i += 256) {
        int b = i + rot; if (b >= n_bins) b -= n_bins;
        u32 h = hist[b];
        if (h) wcur[b] = atomicAdd(&gcur[b * GSTRIDE], h);
    }
    __syncthreads();

    for (int e = tbase + tid; e < tend; e += 256) {    // pass B: LDS place
        int d = dst[e];                                 // L2-hot re-read
        int s = src[e];
        u32 b   = (u32)d >> BIN_SHIFT;
        u32 pos = starts[b] + atomicAdd(&lpos[b], 1u);
        sortbuf[pos] = ((u32)(d & (BIN_NODES - 1)) << 17) | (u32)s;
        binid[pos]   = (u16)b;
    }
    __syncthreads();

    // pass C: linear sweep -> run-coalesced global writes.
    const int cnt = tend - tbase;
    for (int j = tid; j < cnt; j += 256) {
        u32 b   = binid[j];
        u32 rel = wcur[b] + ((u32)j - starts[b]);
        if (rel < CAPBIN)
            cbdata[(size_t)b * CAPBIN + rel] = sortbuf[j];
    }
}

// ---- pass 2: per-bin LDS counting sort by (node, src-block) -> CSR ----
// Sorting each node's segment by src-block makes all aggregate waves walk
// src in roughly the same order -> L2-window locality for the gathers.
__global__ __launch_bounds__(256) void bin_sort_kernel(
    u32* __restrict__ cbdata,          // in: (nid7<<17)|src   out: src (sorted)
    const u32* __restrict__ gcur,
    u32* __restrict__ nodeptr,         // [n_bins*NPTR] absolute offsets
    int n_bins)
{
    __shared__ u32 hist[NSCAN];        // (nid<<3)|srcblk counters, 4 KB
    __shared__ u32 starts[NSCAN];      // 4 KB
    __shared__ u32 lpos[NSCAN];        // 4 KB
    __shared__ u32 sl[CAPBIN];         // 8 KB staging
    __shared__ u32 wsum[4];

    const int tid = threadIdx.x;
    const int bin = blockIdx.x;
    if (bin >= n_bins) return;

    for (int i = tid; i < NSCAN; i += 256) { hist[i] = 0; lpos[i] = 0; }
    __syncthreads();

    int cnt = (int)gcur[bin * GSTRIDE];
    if (cnt > CAPBIN) cnt = CAPBIN;
    u32* bd = cbdata + (size_t)bin * CAPBIN;

    for (int j = tid; j < cnt; j += 256) {             // count
        u32 p = bd[j];
        u32 key = ((p >> 17) << 3) | ((p & 0x1FFFFu) >> SRCSH);
        atomicAdd(&hist[key], 1u);
    }
    __syncthreads();

    // Exclusive scan of hist[0..1024): 4 slots/thread + wave scan (as pass 1).
    {
        const int b0 = tid * 4;
        u32 h0 = hist[b0], h1 = hist[b0+1], h2 = hist[b0+2], h3 = hist[b0+3];
        u32 s  = h0 + h1 + h2 + h3;
        u32 inc = s;
        #pragma unroll
        for (int d = 1; d < 64; d <<= 1) {
            u32 o = __shfl_up(inc, d);
            if ((tid & 63) >= d) inc += o;
        }
        if ((tid & 63) == 63) wsum[tid >> 6] = inc;
        __syncthreads();
        u32 woff = 0;
        #pragma unroll
        for (int k = 0; k < 4; ++k) if (k < (tid >> 6)) woff += wsum[k];
        u32 excl = woff + inc - s;
        starts[b0]   = excl;
        starts[b0+1] = excl + h0;
        starts[b0+2] = excl + h0 + h1;
        starts[b0+3] = excl + h0 + h1 + h2;
    }
    __syncthreads();

    for (int j = tid; j < cnt; j += 256) {             // place into LDS
        u32 p   = bd[j];
        u32 key = ((p >> 17) << 3) | ((p & 0x1FFFFu) >> SRCSH);
        u32 pos = starts[key] + atomicAdd(&lpos[key], 1u);
        sl[pos] = p & 0x1FFFFu;
    }
    __syncthreads();

    const u32 base = (u32)bin * CAPBIN;
    for (int j = tid; j < cnt; j += 256)               // coalesced writeback
        bd[j] = sl[j];
    if (tid < BIN_NODES)
        nodeptr[(size_t)bin * NPTR + tid] = base + starts[tid << 3];
    if (tid == 0)
        nodeptr[(size_t)bin * NPTR + BIN_NODES] = base + (u32)cnt;
}

// ---- aggregate: one 8-lane group per node, CSR spans, no LDS ----
// pass 0: out_bf[node] = bf16(relu(sum))   pass 1: out_f[node] = sum (fp32)
__global__ __launch_bounds__(256) void aggregate_kernel(
    const u16* __restrict__ xin,
    const u32* __restrict__ csorted,   // sorted src ids
    const u32* __restrict__ nodeptr,
    u16* __restrict__ out_bf,
    float* __restrict__ out_f,
    int n_nodes, int pass)
{
    const int tid  = threadIdx.x;

    const int w    = tid >> 6;
    const int lane = tid & 63;
    const int grp  = lane >> 3;
    const int sub  = lane & 7;           // 16B chunk of the 128B bf16 row
    const char* xc = (const char*)xin;

    const int nl   = w * 8 + grp;        // 0..31
    const int node = (int)blockIdx.x * 32 + nl;
    const int bin  = node >> BIN_SHIFT;
    const int nid  = node & (BIN_NODES - 1);

    const int s0  = (int)nodeptr[(size_t)bin * NPTR + nid];
    const int s1  = (int)nodeptr[(size_t)bin * NPTR + nid + 1];

    f32x2 a0={0.f,0.f}, a1={0.f,0.f}, a2={0.f,0.f}, a3={0.f,0.f};

    // Batch-8 id loads (one coalesced load per 8 edges), shfl-broadcast.
    for (int jb = s0; jb < s1; jb += 8) {
        u32 myid = 0;
        if (jb + sub < s1) myid = csorted[jb + sub];
        const int m = min(8, s1 - jb);
        #pragma unroll 1
        for (int k = 0; k < m; ++k) {
            u32 s = (u32)__shfl((int)myid, (lane & 56) + k, 64);
            u32x4 v = *(const u32x4*)(xc + ((size_t)s << 7) + (sub << 4));
            a0 += (f32x2){ __builtin_bit_cast(float, v[0] << 16),
                           __builtin_bit_cast(float, v[0] & 0xFFFF0000u) };
            a1 += (f32x2){ __builtin_bit_cast(float, v[1] << 16),
                           __builtin_bit_cast(float, v[1] & 0xFFFF0000u) };
            a2 += (f32x2){ __builtin_bit_cast(float, v[2] << 16),
                           __builtin_bit_cast(float, v[2] & 0xFFFF0000u) };
            a3 += (f32x2){ __builtin_bit_cast(float, v[3] << 16),
                           __builtin_bit_cast(float, v[3] & 0xFFFF0000u) };
        }
    }

    if (node < n_nodes) {
        if (pass == 0) {                 // 64 lanes x 16B: 8 bf16 rows, relu'd
            u16x8 o;
            o[0]=f2bf(fmaxf(a0.x,0.f)); o[1]=f2bf(fmaxf(a0.y,0.f));
            o[2]=f2bf(fmaxf(a1.x,0.f)); o[3]=f2bf(fmaxf(a1.y,0.f));
            o[4]=f2bf(fmaxf(a2.x,0.f)); o[5]=f2bf(fmaxf(a2.y,0.f));
            o[6]=f2bf(fmaxf(a3.x,0.f)); o[7]=f2bf(fmaxf(a3.y,0.f));
            *(u16x8*)(out_bf + (size_t)node * N_FEAT + sub * 8) = o;
        } else {                         // 64 lanes x 32B: 8 fp32 rows
            float* dp = out_f + (size_t)node * N_FEAT + sub * 8;
            *(float4*)dp       = (float4){a0.x, a0.y, a1.x, a1.y};
            *(float4*)(dp + 4) = (float4){a2.x, a2.y, a3.x, a3.y};
        }
    }
}

extern "C" void kernel_launch(void* const* d_in, const int* in_sizes, int n_in,
                              void* d_out, int out_size, void* d_ws, size_t ws_size,
                              hipStream_t stream) {
    const float* x          = (const float*)d_in[0];
    const int*   edge_index = (const int*)d_in[1];

    const int n_edges = in_sizes[1] / 2;          // (2, N_EDGES) row-major
    const int* src = edge_index;                  // row 0
    const int* dst = edge_index + n_edges;        // row 1

    const int n_nodes = out_size / N_FEAT;                      // 100000
    const int n_bins  = (n_nodes + BIN_NODES - 1) >> BIN_SHIFT; // 782
    float* out = (float*)d_out;

    const size_t xb_bytes    = (size_t)out_size * sizeof(u16);             // 12.8 MB
    const size_t hb_bytes    = (size_t)out_size * sizeof(u16);             // 12.8 MB
    const size_t cb_bytes    = (size_t)n_bins * CAPBIN * sizeof(u32);      // 6.4 MB
    const size_t np_bytes    = (size_t)n_bins * NPTR * sizeof(u32);        // 0.4 MB
    const size_t gcur_bytes  = (size_t)NB_H * GSTRIDE * sizeof(u32);       // 50 KB

    char* w = (char*)d_ws;
    u16* xb      = (u16*)w;              w += xb_bytes;
    u16* hb      = (u16*)w;              w += hb_bytes;
    u32* cbdata  = (u32*)w;              w += cb_bytes;
    u32* nodeptr = (u32*)w;              w += np_bytes;
    u32* gcur    = (u32*)w;

    hipMemsetAsync(gcur, 0, gcur_bytes, stream);

    const int part_blocks = (n_edges + TILE - 1) / TILE;     // 306
    const int conv_blocks = (out_size / 8 + 255) / 256;      // 3125
    partition_convert_kernel<<<part_blocks + conv_blocks, 256, 0, stream>>>(
        x, xb, out_size, src, dst, gcur, cbdata, n_edges, n_bins, part_blocks);

    bin_sort_kernel<<<n_bins, 256, 0, stream>>>(cbdata, gcur, nodeptr, n_bins);

    const int agg_blocks = (n_nodes + 31) / 32;              // 3125
    aggregate_kernel<<<agg_blocks, 256, 0, stream>>>(xb, cbdata, nodeptr, hb, nullptr, n_nodes, 0);
    aggregate_kernel<<<agg_blocks, 256, 0, stream>>>(hb, cbdata, nodeptr, nullptr, out, n_nodes, 1);
}

// Round 9
// 162.559 us; speedup vs baseline: 1.0925x; 1.0434x over previous
//
#include <hip/hip_runtime.h>
#include <hip/hip_bf16.h>

// LightGCN: two rounds of edge aggregation.
//   h[i]   = sum_{e: dst[e]==i} x[src[e]]
//   out[i] = sum_{e: dst[e]==i} relu(h)[src[e]]
//
// Round 21 (aggregate ILP: 8 outstanding row-loads per wave):
//   R19 (degree balance) and R20 (src-ordered gathers) were both null ->
//   aggregate is bound by its INSTRUCTION DEPENDENCY CHAIN, not scheduling
//   or cache locality: the old inner loop had "#pragma unroll 1", i.e.
//   load -> s_waitcnt vmcnt(0) -> 8 fma -> backedge = ONE outstanding
//   row-load per wave, paying full L2/L3 latency (~200-500cy) per edge.
//   Fix: full batches of 8 edges with compile-time unroll -- 8 shfl + 8
//   independent 16B loads issued back-to-back (vmcnt 7->0 as fmas consume),
//   8x memory-level parallelism per wave. Masked tail (<8) unchanged.
//   - src-ordered segments kept from R20 (free; helps once latency hidden).
//   - partition: LDS-sorted tile -> run-coalesced span writes (R17).
//   - ReLU folded into pass-0 aggregate's bf16 write.

#define N_FEAT    64
#define BIN_SHIFT 7
#define BIN_NODES 128
#define CAPBIN    2048             // edges per bin (mean 1600, +11 sigma)
#define NB_H      784              // >= n_bins (782)
#define NSCAN     1024             // padded hist size for the 4-per-thread scan
#define GSTRIDE   16               // one gcur cursor per 64B line
#define TILE      4096
#define NPTR      (BIN_NODES + 1)  // nodeptr entries per bin
#define SRCSH     14               // src subkey shift: 8 blocks of 16K nodes

typedef unsigned int u32;
typedef unsigned short u16;
typedef __attribute__((ext_vector_type(8))) unsigned short u16x8;
typedef __attribute__((ext_vector_type(4))) unsigned int u32x4;
typedef __attribute__((ext_vector_type(2))) float f32x2;

__device__ inline u16 f2bf(float f) {          // RTNE
    u32 u = __builtin_bit_cast(u32, f);
    return (u16)((u + 0x7FFFu + ((u >> 16) & 1u)) >> 16);
}

// ---- pass 1: LDS-sorted tile partition + x->bf16 convert ----
__global__ __launch_bounds__(256) void partition_convert_kernel(
    const float* __restrict__ xf, u16* __restrict__ xb, int n_elems,
    const int* __restrict__ src, const int* __restrict__ dst,
    u32* __restrict__ gcur,        // [n_bins*GSTRIDE] padded cursors (zeroed)
    u32* __restrict__ cbdata,      // [n_bins*CAPBIN] packed (nid7<<17)|src
    int n_edges, int n_bins, int part_blocks)
{
    __shared__ u32 hist[NSCAN];        // 4 KB
    __shared__ u32 starts[NSCAN];      // 4 KB (tile-local exclusive prefix)
    __shared__ u32 lpos[NSCAN];        // 4 KB
    __shared__ u32 wcur[NB_H];         // 3.1 KB (global span base per bin)
    __shared__ u32 sortbuf[TILE];      // 16 KB
    __shared__ u16 binid[TILE];        // 8 KB
    __shared__ u32 wsum[4];

    const int tid = threadIdx.x;

    if ((int)blockIdx.x >= part_blocks) {      // ---- convert x -> bf16 ----
        int i = (((int)blockIdx.x - part_blocks) * 256 + tid) * 8;
        if (i < n_elems) {
            float4 a = *(const float4*)(xf + i);
            float4 b = *(const float4*)(xf + i + 4);
            u16x8 r;
            r[0]=f2bf(a.x); r[1]=f2bf(a.y); r[2]=f2bf(a.z); r[3]=f2bf(a.w);
            r[4]=f2bf(b.x); r[5]=f2bf(b.y); r[6]=f2bf(b.z); r[7]=f2bf(b.w);
            *(u16x8*)(xb + i) = r;
        }
        return;
    }

    const int tbase = (int)blockIdx.x * TILE;
    const int tend  = min(tbase + TILE, n_edges);

    for (int i = tid; i < NSCAN; i += 256) { hist[i] = 0; lpos[i] = 0; }
    __syncthreads();

    for (int e = tbase + tid; e < tend; e += 256)      // pass A: count
        atomicAdd(&hist[(u32)dst[e] >> BIN_SHIFT], 1u);
    __syncthreads();

    // Tile-local exclusive scan of hist[0..NSCAN): 4 slots/thread + wave scan.
    {
        const int b0 = tid * 4;
        u32 h0 = hist[b0], h1 = hist[b0+1], h2 = hist[b0+2], h3 = hist[b0+3];
        u32 s  = h0 + h1 + h2 + h3;
        u32 inc = s;
        #pragma unroll
        for (int d = 1; d < 64; d <<= 1) {
            u32 o = __shfl_up(inc, d);
            if ((tid & 63) >= d) inc += o;
        }
        if ((tid & 63) == 63) wsum[tid >> 6] = inc;
        __syncthreads();
        u32 woff = 0;
        #pragma unroll
        for (int k = 0; k < 4; ++k) if (k < (tid >> 6)) woff += wsum[k];
        u32 excl = woff + inc - s;
        starts[b0]   = excl;
        starts[b0+1] = excl + h0;
        starts[b0+2] = excl + h0 + h1;
        starts[b0+3] = excl + h0 + h1 + h2;
    }
    __syncthreads();

    // Reserve global spans (rotated start to spread cursor-line contention).
    const int rot = (int)(((u32)blockIdx.x * 193u) % (u32)n_bins);
    for (int i = tid; i < n_bins; i += 256) {
        int b = i + rot; if (b >= n_bins) b -= n_bins;
        u32 h = hist[b];
        if (h) wcur[b] = atomicAdd(&gcur[b * GSTRIDE], h);
    }
    __syncthreads();

    for (int e = tbase + tid; e < tend; e += 256) {    // pass B: LDS place
        int d = dst[e];                                 // L2-hot re-read
        int s = src[e];
        u32 b   = (u32)d >> BIN_SHIFT;
        u32 pos = starts[b] + atomicAdd(&lpos[b], 1u);
        sortbuf[pos] = ((u32)(d & (BIN_NODES - 1)) << 17) | (u32)s;
        binid[pos]   = (u16)b;
    }
    __syncthreads();

    // pass C: linear sweep -> run-coalesced global writes.
    const int cnt = tend - tbase;
    for (int j = tid; j < cnt; j += 256) {
        u32 b   = binid[j];
        u32 rel = wcur[b] + ((u32)j - starts[b]);
        if (rel < CAPBIN)
            cbdata[(size_t)b * CAPBIN + rel] = sortbuf[j];
    }
}

// ---- pass 2: per-bin LDS counting sort by (node, src-block) -> CSR ----
__global__ __launch_bounds__(256) void bin_sort_kernel(
    u32* __restrict__ cbdata,          // in: (nid7<<17)|src   out: src (sorted)
    const u32* __restrict__ gcur,
    u32* __restrict__ nodeptr,         // [n_bins*NPTR] absolute offsets
    int n_bins)
{
    __shared__ u32 hist[NSCAN];        // (nid<<3)|srcblk counters, 4 KB
    __shared__ u32 starts[NSCAN];      // 4 KB
    __shared__ u32 lpos[NSCAN];        // 4 KB
    __shared__ u32 sl[CAPBIN];         // 8 KB staging
    __shared__ u32 wsum[4];

    const int tid = threadIdx.x;
    const int bin = blockIdx.x;
    if (bin >= n_bins) return;

    for (int i = tid; i < NSCAN; i += 256) { hist[i] = 0; lpos[i] = 0; }
    __syncthreads();

    int cnt = (int)gcur[bin * GSTRIDE];
    if (cnt > CAPBIN) cnt = CAPBIN;
    u32* bd = cbdata + (size_t)bin * CAPBIN;

    for (int j = tid; j < cnt; j += 256) {             // count
        u32 p = bd[j];
        u32 key = ((p >> 17) << 3) | ((p & 0x1FFFFu) >> SRCSH);
        atomicAdd(&hist[key], 1u);
    }
    __syncthreads();

    // Exclusive scan of hist[0..1024): 4 slots/thread + wave scan.
    {
        const int b0 = tid * 4;
        u32 h0 = hist[b0], h1 = hist[b0+1], h2 = hist[b0+2], h3 = hist[b0+3];
        u32 s  = h0 + h1 + h2 + h3;
        u32 inc = s;
        #pragma unroll
        for (int d = 1; d < 64; d <<= 1) {
            u32 o = __shfl_up(inc, d);
            if ((tid & 63) >= d) inc += o;
        }
        if ((tid & 63) == 63) wsum[tid >> 6] = inc;
        __syncthreads();
        u32 woff = 0;
        #pragma unroll
        for (int k = 0; k < 4; ++k) if (k < (tid >> 6)) woff += wsum[k];
        u32 excl = woff + inc - s;
        starts[b0]   = excl;
        starts[b0+1] = excl + h0;
        starts[b0+2] = excl + h0 + h1;
        starts[b0+3] = excl + h0 + h1 + h2;
    }
    __syncthreads();

    for (int j = tid; j < cnt; j += 256) {             // place into LDS
        u32 p   = bd[j];
        u32 key = ((p >> 17) << 3) | ((p & 0x1FFFFu) >> SRCSH);
        u32 pos = starts[key] + atomicAdd(&lpos[key], 1u);
        sl[pos] = p & 0x1FFFFu;
    }
    __syncthreads();

    const u32 base = (u32)bin * CAPBIN;
    for (int j = tid; j < cnt; j += 256)               // coalesced writeback
        bd[j] = sl[j];
    if (tid < BIN_NODES)
        nodeptr[(size_t)bin * NPTR + tid] = base + starts[tid << 3];
    if (tid == 0)
        nodeptr[(size_t)bin * NPTR + BIN_NODES] = base + (u32)cnt;
}

// ---- aggregate: one 8-lane group per node, CSR spans, no LDS ----
// pass 0: out_bf[node] = bf16(relu(sum))   pass 1: out_f[node] = sum (fp32)
__global__ __launch_bounds__(256) void aggregate_kernel(
    const u16* __restrict__ xin,
    const u32* __restrict__ csorted,   // sorted src ids
    const u32* __restrict__ nodeptr,
    u16* __restrict__ out_bf,
    float* __restrict__ out_f,
    int n_nodes, int pass)
{
    const int tid  = threadIdx.x;

    const int w    = tid >> 6;
    const int lane = tid & 63;
    const int grp  = lane >> 3;
    const int sub  = lane & 7;           // 16B chunk of the 128B bf16 row
    const char* xc = (const char*)xin;

    const int nl   = w * 8 + grp;        // 0..31
    const int node = (int)blockIdx.x * 32 + nl;
    const int bin  = node >> BIN_SHIFT;
    const int nid  = node & (BIN_NODES - 1);

    const int s0  = (int)nodeptr[(size_t)bin * NPTR + nid];
    const int s1  = (int)nodeptr[(size_t)bin * NPTR + nid + 1];

    f32x2 a0={0.f,0.f}, a1={0.f,0.f}, a2={0.f,0.f}, a3={0.f,0.f};

    // Full batches of 8: compile-time unroll -> 8 independent row loads in
    // flight per wave (vmcnt 7..0), instead of 1 (the R17-R20 serial chain).
    int jb = s0;
    for (; jb + 8 <= s1; jb += 8) {
        u32 myid = csorted[jb + sub];
        #pragma unroll
        for (int k = 0; k < 8; ++k) {
            u32 s = (u32)__shfl((int)myid, (lane & 56) + k, 64);
            u32x4 v = *(const u32x4*)(xc + ((size_t)s << 7) + (sub << 4));
            a0 += (f32x2){ __builtin_bit_cast(float, v[0] << 16),
                           __builtin_bit_cast(float, v[0] & 0xFFFF0000u) };
            a1 += (f32x2){ __builtin_bit_cast(float, v[1] << 16),
                           __builtin_bit_cast(float, v[1] & 0xFFFF0000u) };
            a2 += (f32x2){ __builtin_bit_cast(float, v[2] << 16),
                           __builtin_bit_cast(float, v[2] & 0xFFFF0000u) };
            a3 += (f32x2){ __builtin_bit_cast(float, v[3] << 16),
                           __builtin_bit_cast(float, v[3] & 0xFFFF0000u) };
        }
    }
    if (jb < s1) {                       // masked tail (< 8 edges)
        u32 myid = 0;
        if (jb + sub < s1) myid = csorted[jb + sub];
        const int m = s1 - jb;
        #pragma unroll 1
        for (int k = 0; k < m; ++k) {
            u32 s = (u32)__shfl((int)myid, (lane & 56) + k, 64);
            u32x4 v = *(const u32x4*)(xc + ((size_t)s << 7) + (sub << 4));
            a0 += (f32x2){ __builtin_bit_cast(float, v[0] << 16),
                           __builtin_bit_cast(float, v[0] & 0xFFFF0000u) };
            a1 += (f32x2){ __builtin_bit_cast(float, v[1] << 16),
                           __builtin_bit_cast(float, v[1] & 0xFFFF0000u) };
            a2 += (f32x2){ __builtin_bit_cast(float, v[2] << 16),
                           __builtin_bit_cast(float, v[2] & 0xFFFF0000u) };
            a3 += (f32x2){ __builtin_bit_cast(float, v[3] << 16),
                           __builtin_bit_cast(float, v[3] & 0xFFFF0000u) };
        }
    }

    if (node < n_nodes) {
        if (pass == 0) {                 // 64 lanes x 16B: 8 bf16 rows, relu'd
            u16x8 o;
            o[0]=f2bf(fmaxf(a0.x,0.f)); o[1]=f2bf(fmaxf(a0.y,0.f));
            o[2]=f2bf(fmaxf(a1.x,0.f)); o[3]=f2bf(fmaxf(a1.y,0.f));
            o[4]=f2bf(fmaxf(a2.x,0.f)); o[5]=f2bf(fmaxf(a2.y,0.f));
            o[6]=f2bf(fmaxf(a3.x,0.f)); o[7]=f2bf(fmaxf(a3.y,0.f));
            *(u16x8*)(out_bf + (size_t)node * N_FEAT + sub * 8) = o;
        } else {                         // 64 lanes x 32B: 8 fp32 rows
            float* dp = out_f + (size_t)node * N_FEAT + sub * 8;
            *(float4*)dp       = (float4){a0.x, a0.y, a1.x, a1.y};
            *(float4*)(dp + 4) = (float4){a2.x, a2.y, a3.x, a3.y};
        }
    }
}

extern "C" void kernel_launch(void* const* d_in, const int* in_sizes, int n_in,
                              void* d_out, int out_size, void* d_ws, size_t ws_size,
                              hipStream_t stream) {
    const float* x          = (const float*)d_in[0];
    const int*   edge_index = (const int*)d_in[1];

    const int n_edges = in_sizes[1] / 2;          // (2, N_EDGES) row-major
    const int* src = edge_index;                  // row 0
    const int* dst = edge_index + n_edges;        // row 1

    const int n_nodes = out_size / N_FEAT;                      // 100000
    const int n_bins  = (n_nodes + BIN_NODES - 1) >> BIN_SHIFT; // 782
    float* out = (float*)d_out;

    const size_t xb_bytes    = (size_t)out_size * sizeof(u16);             // 12.8 MB
    const size_t hb_bytes    = (size_t)out_size * sizeof(u16);             // 12.8 MB
    const size_t cb_bytes    = (size_t)n_bins * CAPBIN * sizeof(u32);      // 6.4 MB
    const size_t np_bytes    = (size_t)n_bins * NPTR * sizeof(u32);        // 0.4 MB
    const size_t gcur_bytes  = (size_t)NB_H * GSTRIDE * sizeof(u32);       // 50 KB

    char* w = (char*)d_ws;
    u16* xb      = (u16*)w;              w += xb_bytes;
    u16* hb      = (u16*)w;              w += hb_bytes;
    u32* cbdata  = (u32*)w;              w += cb_bytes;
    u32* nodeptr = (u32*)w;              w += np_bytes;
    u32* gcur    = (u32*)w;

    hipMemsetAsync(gcur, 0, gcur_bytes, stream);

    const int part_blocks = (n_edges + TILE - 1) / TILE;     // 306
    const int conv_blocks = (out_size / 8 + 255) / 256;      // 3125
    partition_convert_kernel<<<part_blocks + conv_blocks, 256, 0, stream>>>(
        x, xb, out_size, src, dst, gcur, cbdata, n_edges, n_bins, part_blocks);

    bin_sort_kernel<<<n_bins, 256, 0, stream>>>(cbdata, gcur, nodeptr, n_bins);

    const int agg_blocks = (n_nodes + 31) / 32;              // 3125
    aggregate_kernel<<<agg_blocks, 256, 0, stream>>>(xb, cbdata, nodeptr, hb, nullptr, n_nodes, 0);
    aggregate_kernel<<<agg_blocks, 256, 0, stream>>>(hb, cbdata, nodeptr, nullptr, out, n_nodes, 1);
}